// Round 4
// baseline (3123.423 us; speedup 1.0000x reference)
//
#include <hip/hip_runtime.h>
#include <hip/hip_bf16.h>

// Swin-V2 window attention. B=2048 windows, N=64 tokens, CH=512, H=16 heads,
// d=32, NW=256 masks. bf16 MFMA 16x16x32, f32 accumulation.
//
// Round-4: Round-3 structure with the proj_gemm staging bug fixed (loop
// covered only rows 0..31 of the O tile; i<8 -> i<16).
//   xcast:    x f32 -> bf16, stored in d_out's per-window 2nd half (no ws growth)
//   win_attn: 256 thr / 4 waves, wave = 1 head x 4 rounds. No x LDS tile
//             (A-frags from global bf16 x, L2-hot). LDS = 12 KB/wave scratch
//             = 48 KB -> 3 blocks/CU = 3 waves/SIMD. No barriers at all.
//             Writes O bf16 into d_out's per-window 1st half.
//   proj_gemm: per-window 64x512 GEMM. Stages O16 -> LDS (swizzled) then
//             overwrites the window region with f32 out.
//
// ws layout (2.38 MB, unchanged):
//   [0)        bias_tab f32 [16][64][64]   = 262144 B
//   [262144)   wqkv_t  bf16 [1536][512]    = 1572864 B  (w_qkv^T, n-major)
//   [1835008)  proj_t  bf16 [512][512]     = 524288 B   (proj_w^T, n-major)
//   [2359296)  tab225  f32 [225][16]       = 14400 B

typedef __attribute__((ext_vector_type(4))) float f32x4;
typedef __attribute__((ext_vector_type(8))) __bf16 bf16x8;

#define MFMA16(a, b, c) __builtin_amdgcn_mfma_f32_16x16x32_bf16((a), (b), (c), 0, 0, 0)

__device__ __forceinline__ unsigned short f2bf(float f) {
  union { float f; unsigned u; } v; v.f = f;
  unsigned r = v.u + 0x7fffu + ((v.u >> 16) & 1u);   // round-to-nearest-even
  return (unsigned short)(r >> 16);
}

// ---- swizzled LDS element-index helpers (same map on write and read) ----
// [.][512] rows: permute 16B chunks within row by row&7.
__device__ __forceinline__ int xsw(int r, int k) {
  return r * 512 + ((((k >> 3) ^ (r & 7)) << 3) | (k & 7));
}
// 32-col slots (Qn/Kn/O) [64][32].
__device__ __forceinline__ int qsw(int r, int c) {
  return r * 32 + ((((c >> 3) ^ ((r >> 1) & 3)) << 3) | (c & 7));
}
// 64-col slots (V^T [32][64], P [64][64]).
__device__ __forceinline__ int psw(int r, int c) {
  return r * 64 + ((((c >> 3) ^ (r & 7)) << 3) | (c & 7));
}

// ---------------------------------------------------------------- prep1
__global__ void prep1(const float* __restrict__ rel_table,
                      const float* __restrict__ w_qkv,
                      const float* __restrict__ proj_w,
                      const float* __restrict__ cpb_w1,
                      const float* __restrict__ cpb_b1,
                      const float* __restrict__ cpb_w2,
                      unsigned short* __restrict__ wqkv_t,
                      unsigned short* __restrict__ proj_t,
                      float* __restrict__ tab225) {
  const int bid = blockIdx.x, tid = threadIdx.x;
  __shared__ float red[4][16];
  if (bid < 225) {
    const float t0 = rel_table[bid * 2], t1 = rel_table[bid * 2 + 1];
    float acc[16];
#pragma unroll
    for (int h = 0; h < 16; ++h) acc[h] = 0.f;
    for (int j = tid; j < 512; j += 256) {
      const float hj = fmaxf(t0 * cpb_w1[j] + t1 * cpb_w1[512 + j] + cpb_b1[j], 0.f);
#pragma unroll
      for (int h = 0; h < 16; ++h) acc[h] += hj * cpb_w2[j * 16 + h];
    }
    const int lane = tid & 63, w = tid >> 6;
#pragma unroll
    for (int h = 0; h < 16; ++h) {
      float v = acc[h];
      for (int m = 1; m < 64; m <<= 1) v += __shfl_xor(v, m);
      if (lane == 0) red[w][h] = v;
    }
    __syncthreads();
    if (tid < 16)
      tab225[bid * 16 + tid] = red[0][tid] + red[1][tid] + red[2][tid] + red[3][tid];
  } else if (bid < 225 + 1536) {
    const int n = bid - 225;
    for (int k = tid; k < 512; k += 256)
      wqkv_t[n * 512 + k] = f2bf(w_qkv[(size_t)k * 1536 + n]);
  } else {
    const int n = bid - 1761;
    for (int k = tid; k < 512; k += 256)
      proj_t[n * 512 + k] = f2bf(proj_w[(size_t)k * 512 + n]);
  }
}

// ---------------------------------------------------------------- prep2
__global__ void prep2(const float* __restrict__ tab225, float* __restrict__ bias_tab) {
  const int h = blockIdx.x, tid = threadIdx.x;
  for (int e = tid; e < 4096; e += 256) {
    const int n = e >> 6, m = e & 63;
    const int dr = (n >> 3) - (m >> 3) + 7;
    const int dc = (n & 7) - (m & 7) + 7;
    const float v = tab225[(dr * 15 + dc) * 16 + h];
    bias_tab[h * 4096 + e] = 16.f / (1.f + __expf(-v));
  }
}

// ---------------------------------------------------------------- xcast
// x f32 [2048][64][512] -> bf16, stored at d_out window-region 2nd half:
// ushort idx = w*65536 + 32768 + (r*512+k).
__global__ __launch_bounds__(256) void xcast(const float* __restrict__ x,
                                             unsigned short* __restrict__ outu) {
  const int tid = threadIdx.x;
  const float4* xg = (const float4*)x;
#pragma unroll
  for (int i = 0; i < 16; ++i) {
    const size_t e4 = (size_t)blockIdx.x * 4096 + i * 256 + tid;  // float4 index
    const float4 v = xg[e4];
    const size_t w = e4 >> 13;          // window
    const size_t f4in = e4 & 8191;      // float4 within window
    ushort4 pk;
    pk.x = f2bf(v.x); pk.y = f2bf(v.y); pk.z = f2bf(v.z); pk.w = f2bf(v.w);
    *(ushort4*)&outu[w * 65536 + 32768 + f4in * 4] = pk;
  }
}

// ---------------------------------------------------------------- win_attn
// 4 waves, wave w does heads h = rnd*4+w for rnd=0..3. All LDS wave-private,
// no barriers. Reads x16 from window 2nd half, writes O16 to window 1st half.
__global__ __launch_bounds__(256, 3) void win_attn(
    const float* __restrict__ mask,
    const float* __restrict__ q_bias,
    const float* __restrict__ v_bias,
    const float* __restrict__ logit_scale,
    const unsigned short* __restrict__ wqkv_t,
    const float* __restrict__ bias_tab,
    unsigned short* __restrict__ outu) {
  __shared__ __align__(16) unsigned short sc[4][3 * 2048];  // 48 KB: per-wave Q|K|slot3

  const int tid = threadIdx.x;
  const int wid = tid >> 6;
  const int lane = tid & 63;
  const int c16 = lane & 15;
  const int g = lane >> 4;
  const int b = blockIdx.x;

  const unsigned short* xw = outu + (size_t)b * 65536 + 32768;  // x16 [64][512]
  unsigned short* ow = outu + (size_t)b * 65536;                // O16 [64][512]

  unsigned short* q_s = sc[wid];            // Qn [64][32] (qsw)
  unsigned short* k_s = sc[wid] + 2048;     // Kn [64][32] (qsw)
  unsigned short* v_slot = sc[wid] + 4096;  // V^T [32][64] (psw), then O [64][32] (qsw)
  unsigned short* p_s = sc[wid];            // P [64][64] (psw) overlays Q|K

  const f32x4 zacc = {0.f, 0.f, 0.f, 0.f};
  const float* mk = mask + (size_t)(b & 255) * 4096;

  for (int rnd = 0; rnd < 4; ++rnd) {
    const int h = rnd * 4 + wid;
    const float scale_h = __expf(fminf(logit_scale[h], 4.6051701859880914f));
    const unsigned short* wq = wqkv_t + (size_t)(h * 32) * 512;
    const unsigned short* wk = wqkv_t + (size_t)(512 + h * 32) * 512;
    const unsigned short* wv = wqkv_t + (size_t)(1024 + h * 32) * 512;

    // ---- Stage A1: Q,K = x @ Wq_h, x @ Wk_h  (256 MFMA)
    {
      f32x4 aq[4][2], ak[4][2];
#pragma unroll
      for (int mt = 0; mt < 4; ++mt)
#pragma unroll
        for (int nt = 0; nt < 2; ++nt) { aq[mt][nt] = zacc; ak[mt][nt] = zacc; }
#pragma unroll
      for (int ks = 0; ks < 16; ++ks) {
        const int k0 = ks * 32 + g * 8;
        bf16x8 A[4];
#pragma unroll
        for (int mt = 0; mt < 4; ++mt)
          A[mt] = *(const bf16x8*)&xw[(mt * 16 + c16) * 512 + k0];
#pragma unroll
        for (int nt = 0; nt < 2; ++nt) {
          const int ro = (nt * 16 + c16) * 512 + k0;
          const bf16x8 Bq = *(const bf16x8*)&wq[ro];
          const bf16x8 Bk = *(const bf16x8*)&wk[ro];
#pragma unroll
          for (int mt = 0; mt < 4; ++mt) {
            aq[mt][nt] = MFMA16(A[mt], Bq, aq[mt][nt]);
            ak[mt][nt] = MFMA16(A[mt], Bk, ak[mt][nt]);
          }
        }
      }
      const float qb0 = q_bias[h * 32 + c16];
      const float qb1 = q_bias[h * 32 + 16 + c16];
#pragma unroll
      for (int mt = 0; mt < 4; ++mt) {
#pragma unroll
        for (int j = 0; j < 4; ++j) {
          const int row = mt * 16 + g * 4 + j;  // C layout: row=(lane>>4)*4+reg
          float q0 = aq[mt][0][j] + qb0;
          float q1 = aq[mt][1][j] + qb1;
          float ss = q0 * q0 + q1 * q1;
          ss += __shfl_xor(ss, 1); ss += __shfl_xor(ss, 2);
          ss += __shfl_xor(ss, 4); ss += __shfl_xor(ss, 8);
          const float rn = scale_h * rsqrtf(ss);
          q_s[qsw(row, c16)] = f2bf(q0 * rn);
          q_s[qsw(row, 16 + c16)] = f2bf(q1 * rn);
          const float k0v = ak[mt][0][j];
          const float k1v = ak[mt][1][j];
          float sk = k0v * k0v + k1v * k1v;
          sk += __shfl_xor(sk, 1); sk += __shfl_xor(sk, 2);
          sk += __shfl_xor(sk, 4); sk += __shfl_xor(sk, 8);
          const float rk = rsqrtf(sk);
          k_s[qsw(row, c16)] = f2bf(k0v * rk);
          k_s[qsw(row, 16 + c16)] = f2bf(k1v * rk);
        }
      }
    }

    // ---- Stage A2: V = x @ Wv_h  (128 MFMA), stored transposed [d][token]
    {
      f32x4 av[4][2];
#pragma unroll
      for (int mt = 0; mt < 4; ++mt)
#pragma unroll
        for (int nt = 0; nt < 2; ++nt) av[mt][nt] = zacc;
#pragma unroll
      for (int ks = 0; ks < 16; ++ks) {
        const int k0 = ks * 32 + g * 8;
        bf16x8 A[4];
#pragma unroll
        for (int mt = 0; mt < 4; ++mt)
          A[mt] = *(const bf16x8*)&xw[(mt * 16 + c16) * 512 + k0];
#pragma unroll
        for (int nt = 0; nt < 2; ++nt) {
          const bf16x8 Bv = *(const bf16x8*)&wv[(nt * 16 + c16) * 512 + k0];
#pragma unroll
          for (int mt = 0; mt < 4; ++mt)
            av[mt][nt] = MFMA16(A[mt], Bv, av[mt][nt]);
        }
      }
      const float vb0 = v_bias[h * 32 + c16];
      const float vb1 = v_bias[h * 32 + 16 + c16];
#pragma unroll
      for (int mt = 0; mt < 4; ++mt) {
#pragma unroll
        for (int j = 0; j < 4; ++j) {
          const int row = mt * 16 + g * 4 + j;
          v_slot[psw(c16, row)] = f2bf(av[mt][0][j] + vb0);
          v_slot[psw(16 + c16, row)] = f2bf(av[mt][1][j] + vb1);
        }
      }
    }

    // ---- Stage B: S = Qn @ Kn^T (16 MFMA), + CPB bias + mask, softmax
    f32x4 S[4][4];
    {
      bf16x8 A[4], Bk4[4];
#pragma unroll
      for (int mt = 0; mt < 4; ++mt)
        A[mt] = *(const bf16x8*)&q_s[qsw(mt * 16 + c16, g * 8)];
#pragma unroll
      for (int nt = 0; nt < 4; ++nt)
        Bk4[nt] = *(const bf16x8*)&k_s[qsw(nt * 16 + c16, g * 8)];
#pragma unroll
      for (int mt = 0; mt < 4; ++mt)
#pragma unroll
        for (int nt = 0; nt < 4; ++nt)
          S[mt][nt] = MFMA16(A[mt], Bk4[nt], zacc);
    }
    const float* bt = bias_tab + (size_t)h * 4096;
#pragma unroll
    for (int mt = 0; mt < 4; ++mt)
#pragma unroll
      for (int j = 0; j < 4; ++j) {
        const int r = mt * 16 + g * 4 + j;
#pragma unroll
        for (int nt = 0; nt < 4; ++nt) {
          const int c = nt * 16 + c16;
          S[mt][nt][j] += bt[r * 64 + c] + mk[r * 64 + c];
        }
      }
#pragma unroll
    for (int mt = 0; mt < 4; ++mt)
#pragma unroll
      for (int j = 0; j < 4; ++j) {
        float m0 = fmaxf(fmaxf(S[mt][0][j], S[mt][1][j]), fmaxf(S[mt][2][j], S[mt][3][j]));
        m0 = fmaxf(m0, __shfl_xor(m0, 1));
        m0 = fmaxf(m0, __shfl_xor(m0, 2));
        m0 = fmaxf(m0, __shfl_xor(m0, 4));
        m0 = fmaxf(m0, __shfl_xor(m0, 8));
        float sum = 0.f;
#pragma unroll
        for (int nt = 0; nt < 4; ++nt) {
          const float p = __expf(S[mt][nt][j] - m0);
          S[mt][nt][j] = p;
          sum += p;
        }
        sum += __shfl_xor(sum, 1); sum += __shfl_xor(sum, 2);
        sum += __shfl_xor(sum, 4); sum += __shfl_xor(sum, 8);
        const float inv = 1.f / sum;
        const int r = mt * 16 + g * 4 + j;
#pragma unroll
        for (int nt = 0; nt < 4; ++nt)
          p_s[psw(r, nt * 16 + c16)] = f2bf(S[mt][nt][j] * inv);
      }

    // ---- Stage C: O = P @ V (16 MFMA), O -> v_slot (V^T dead after reads)
    f32x4 O[4][2];
#pragma unroll
    for (int mt = 0; mt < 4; ++mt)
#pragma unroll
      for (int nt = 0; nt < 2; ++nt) O[mt][nt] = zacc;
#pragma unroll
    for (int ks = 0; ks < 2; ++ks) {
      bf16x8 A[4], B2[2];
#pragma unroll
      for (int mt = 0; mt < 4; ++mt)
        A[mt] = *(const bf16x8*)&p_s[psw(mt * 16 + c16, ks * 32 + g * 8)];
#pragma unroll
      for (int nt = 0; nt < 2; ++nt)
        B2[nt] = *(const bf16x8*)&v_slot[psw(nt * 16 + c16, ks * 32 + g * 8)];
#pragma unroll
      for (int mt = 0; mt < 4; ++mt)
#pragma unroll
        for (int nt = 0; nt < 2; ++nt)
          O[mt][nt] = MFMA16(A[mt], B2[nt], O[mt][nt]);
    }
#pragma unroll
    for (int mt = 0; mt < 4; ++mt)
#pragma unroll
      for (int j = 0; j < 4; ++j) {
        const int row = mt * 16 + g * 4 + j;
        v_slot[qsw(row, c16)] = f2bf(O[mt][0][j]);
        v_slot[qsw(row, 16 + c16)] = f2bf(O[mt][1][j]);
      }

    // ---- O store: wave-private LDS -> global, 8 B row segments
#pragma unroll
    for (int i = 0; i < 8; ++i) {
      const int chunk = i * 64 + lane;
      const int r = chunk >> 3;
      const int c4 = (chunk & 7) << 2;
      const ushort4 v = *(const ushort4*)&v_slot[qsw(r, c4)];
      *(ushort4*)&ow[r * 512 + h * 32 + c4] = v;
    }
  }
}

// ---------------------------------------------------------------- proj_gemm
// Per window: stage O16 [64][512] -> LDS (xsw), then out = O @ proj_t + b,
// overwriting the window region with f32. 4 waves, each does two 64-col strips.
__global__ __launch_bounds__(256, 2) void proj_gemm(
    const unsigned short* __restrict__ proj_t,
    const float* __restrict__ proj_b,
    float* __restrict__ out) {
  __shared__ __align__(16) unsigned short o_s[64 * 512];  // 64 KB

  const int tid = threadIdx.x;
  const int wid = tid >> 6;
  const int lane = tid & 63;
  const int c16 = lane & 15;
  const int g = lane >> 4;
  const int b = blockIdx.x;

  const unsigned short* ow = (const unsigned short*)out + (size_t)b * 65536;
  float* og = out + (size_t)b * 32768;

  // stage O16 -> LDS swizzled: 4096 chunks of 8 ushorts (full 64x512 tile)
#pragma unroll
  for (int i = 0; i < 16; ++i) {
    const int ch = i * 256 + tid;          // 8-ushort chunk id, 4096 total
    const int r = ch >> 6;                 // 64 chunks of 8 per row
    const int k = (ch & 63) << 3;
    const ushort4 lo = *(const ushort4*)&ow[ch * 8];
    const ushort4 hi = *(const ushort4*)&ow[ch * 8 + 4];
    *(ushort4*)&o_s[xsw(r, k)] = lo;
    *(ushort4*)&o_s[xsw(r, k) + 4] = hi;
  }
  __syncthreads();

  const f32x4 zacc = {0.f, 0.f, 0.f, 0.f};
#pragma unroll
  for (int half = 0; half < 2; ++half) {
    const int c0 = half * 256 + wid * 64;
    f32x4 outacc[4][4];
#pragma unroll
    for (int mt = 0; mt < 4; ++mt)
#pragma unroll
      for (int nt = 0; nt < 4; ++nt) outacc[mt][nt] = zacc;
#pragma unroll
    for (int ks = 0; ks < 16; ++ks) {
      const int k0 = ks * 32 + g * 8;
      bf16x8 A[4];
#pragma unroll
      for (int mt = 0; mt < 4; ++mt)
        A[mt] = *(const bf16x8*)&o_s[xsw(mt * 16 + c16, k0)];
#pragma unroll
      for (int nt = 0; nt < 4; ++nt) {
        const bf16x8 Bf = *(const bf16x8*)&proj_t[(size_t)(c0 + nt * 16 + c16) * 512 + k0];
#pragma unroll
        for (int mt = 0; mt < 4; ++mt)
          outacc[mt][nt] = MFMA16(A[mt], Bf, outacc[mt][nt]);
      }
    }
    // f32 writes clobber O16 bytes, but all O reads come from LDS -> safe.
#pragma unroll
    for (int nt = 0; nt < 4; ++nt) {
      const int c = c0 + nt * 16 + c16;
      const float pb = proj_b[c];
#pragma unroll
      for (int mt = 0; mt < 4; ++mt) {
#pragma unroll
        for (int j = 0; j < 4; ++j) {
          const int r = mt * 16 + g * 4 + j;
          og[r * 512 + c] = outacc[mt][nt][j] + pb;
        }
      }
    }
  }
}

// ---------------------------------------------------------------- launch
extern "C" void kernel_launch(void* const* d_in, const int* in_sizes, int n_in,
                              void* d_out, int out_size, void* d_ws, size_t ws_size,
                              hipStream_t stream) {
  const float* x = (const float*)d_in[0];
  const float* mask = (const float*)d_in[1];
  const float* rel_table = (const float*)d_in[2];
  const float* w_qkv = (const float*)d_in[3];
  const float* q_bias = (const float*)d_in[4];
  const float* v_bias = (const float*)d_in[5];
  const float* logit_scale = (const float*)d_in[6];
  const float* cpb_w1 = (const float*)d_in[7];
  const float* cpb_b1 = (const float*)d_in[8];
  const float* cpb_w2 = (const float*)d_in[9];
  const float* proj_w = (const float*)d_in[10];
  const float* proj_b = (const float*)d_in[11];

  char* ws = (char*)d_ws;
  float* bias_tab = (float*)(ws);
  unsigned short* wqkv_t = (unsigned short*)(ws + 262144);
  unsigned short* proj_t = (unsigned short*)(ws + 262144 + 1572864);
  float* tab225 = (float*)(ws + 262144 + 1572864 + 524288);

  unsigned short* outu = (unsigned short*)d_out;

  prep1<<<2273, 256, 0, stream>>>(rel_table, w_qkv, proj_w, cpb_w1, cpb_b1, cpb_w2,
                                  wqkv_t, proj_t, tab225);
  prep2<<<16, 256, 0, stream>>>(tab225, bias_tab);
  xcast<<<4096, 256, 0, stream>>>(x, outu);
  win_attn<<<2048, 256, 0, stream>>>(mask, q_bias, v_bias, logit_scale,
                                     wqkv_t, bias_tab, outu);
  proj_gemm<<<2048, 256, 0, stream>>>(proj_t, proj_b, (float*)d_out);
}

// Round 5
// 2267.249 us; speedup vs baseline: 1.3776x; 1.3776x over previous
//
#include <hip/hip_runtime.h>
#include <hip/hip_bf16.h>

// Swin-V2 window attention. B=2048 windows, N=64 tokens, CH=512, H=16 heads,
// d=32, NW=256 masks. bf16 MFMA 16x16x32, f32 accumulation.
//
// Round-5: Round-4 minus the x-reread disaster. win_attn stages x (f32 ->
// bf16) into LDS ONCE per block (Round-4 read x from global per A-frag:
// 2.14 GB HBM fetch, 16x ideal, pure HBM-bound). 8 waves / 512 thr, wave =
// 1 head x 2 rounds. LDS = x_s 64 KB + 8 x 12 KB wave scratch = 160 KB max
// -> 1 block/CU, 2 waves/SIMD. Projection stays a separate kernel so no
// stage's live set exceeds ~110 VGPRs (Rounds 1/2 spilled because outacc
// coexisted with QKV accumulators). xcast kernel dropped (fused into stage).
//
//   win_attn:  writes O bf16 into d_out's per-window 1st half (64 KB of 128).
//   proj_gemm: stages O16 -> LDS (swizzled), then overwrites window with f32.
//
// ws layout (2.38 MB):
//   [0)        bias_tab f32 [16][64][64]   = 262144 B
//   [262144)   wqkv_t  bf16 [1536][512]    = 1572864 B  (w_qkv^T, n-major)
//   [1835008)  proj_t  bf16 [512][512]     = 524288 B   (proj_w^T, n-major)
//   [2359296)  tab225  f32 [225][16]       = 14400 B

typedef __attribute__((ext_vector_type(4))) float f32x4;
typedef __attribute__((ext_vector_type(8))) __bf16 bf16x8;

#define MFMA16(a, b, c) __builtin_amdgcn_mfma_f32_16x16x32_bf16((a), (b), (c), 0, 0, 0)

__device__ __forceinline__ unsigned short f2bf(float f) {
  union { float f; unsigned u; } v; v.f = f;
  unsigned r = v.u + 0x7fffu + ((v.u >> 16) & 1u);   // round-to-nearest-even
  return (unsigned short)(r >> 16);
}

// ---- swizzled LDS element-index helpers (same map on write and read) ----
// [.][512] rows: permute 16B chunks within row by row&7.
__device__ __forceinline__ int xsw(int r, int k) {
  return r * 512 + ((((k >> 3) ^ (r & 7)) << 3) | (k & 7));
}
// 32-col slots (Qn/Kn/O) [64][32].
__device__ __forceinline__ int qsw(int r, int c) {
  return r * 32 + ((((c >> 3) ^ ((r >> 1) & 3)) << 3) | (c & 7));
}
// 64-col slots (V^T [32][64], P [64][64]).
__device__ __forceinline__ int psw(int r, int c) {
  return r * 64 + ((((c >> 3) ^ (r & 7)) << 3) | (c & 7));
}

// ---------------------------------------------------------------- prep1
__global__ void prep1(const float* __restrict__ rel_table,
                      const float* __restrict__ w_qkv,
                      const float* __restrict__ proj_w,
                      const float* __restrict__ cpb_w1,
                      const float* __restrict__ cpb_b1,
                      const float* __restrict__ cpb_w2,
                      unsigned short* __restrict__ wqkv_t,
                      unsigned short* __restrict__ proj_t,
                      float* __restrict__ tab225) {
  const int bid = blockIdx.x, tid = threadIdx.x;
  __shared__ float red[4][16];
  if (bid < 225) {
    const float t0 = rel_table[bid * 2], t1 = rel_table[bid * 2 + 1];
    float acc[16];
#pragma unroll
    for (int h = 0; h < 16; ++h) acc[h] = 0.f;
    for (int j = tid; j < 512; j += 256) {
      const float hj = fmaxf(t0 * cpb_w1[j] + t1 * cpb_w1[512 + j] + cpb_b1[j], 0.f);
#pragma unroll
      for (int h = 0; h < 16; ++h) acc[h] += hj * cpb_w2[j * 16 + h];
    }
    const int lane = tid & 63, w = tid >> 6;
#pragma unroll
    for (int h = 0; h < 16; ++h) {
      float v = acc[h];
      for (int m = 1; m < 64; m <<= 1) v += __shfl_xor(v, m);
      if (lane == 0) red[w][h] = v;
    }
    __syncthreads();
    if (tid < 16)
      tab225[bid * 16 + tid] = red[0][tid] + red[1][tid] + red[2][tid] + red[3][tid];
  } else if (bid < 225 + 1536) {
    const int n = bid - 225;
    for (int k = tid; k < 512; k += 256)
      wqkv_t[n * 512 + k] = f2bf(w_qkv[(size_t)k * 1536 + n]);
  } else {
    const int n = bid - 1761;
    for (int k = tid; k < 512; k += 256)
      proj_t[n * 512 + k] = f2bf(proj_w[(size_t)k * 512 + n]);
  }
}

// ---------------------------------------------------------------- prep2
__global__ void prep2(const float* __restrict__ tab225, float* __restrict__ bias_tab) {
  const int h = blockIdx.x, tid = threadIdx.x;
  for (int e = tid; e < 4096; e += 256) {
    const int n = e >> 6, m = e & 63;
    const int dr = (n >> 3) - (m >> 3) + 7;
    const int dc = (n & 7) - (m & 7) + 7;
    const float v = tab225[(dr * 15 + dc) * 16 + h];
    bias_tab[h * 4096 + e] = 16.f / (1.f + __expf(-v));
  }
}

// ---------------------------------------------------------------- win_attn
// 8 waves, wave w does heads h = rnd*8+w for rnd=0..1. x staged to LDS once
// (single barrier); all other LDS wave-private. Writes O16 to d_out window
// 1st half.
__global__ __launch_bounds__(512) void win_attn(
    const float* __restrict__ x,
    const float* __restrict__ mask,
    const float* __restrict__ q_bias,
    const float* __restrict__ v_bias,
    const float* __restrict__ logit_scale,
    const unsigned short* __restrict__ wqkv_t,
    const float* __restrict__ bias_tab,
    unsigned short* __restrict__ outu) {
  __shared__ __align__(16) unsigned short x_s[64 * 512];    // 65536 B (xsw)
  __shared__ __align__(16) unsigned short sc[8][3 * 2048];  // 98304 B wave scratch

  const int tid = threadIdx.x;
  const int wid = tid >> 6;     // 0..7
  const int lane = tid & 63;
  const int c16 = lane & 15;
  const int g = lane >> 4;
  const int b = blockIdx.x;

  // Phase 0: stage x window f32 -> bf16 into swizzled LDS (coalesced float4).
  {
    const float4* xg = (const float4*)(x + (size_t)b * (64 * 512));
#pragma unroll
    for (int it = 0; it < 16; ++it) {
      const int e4 = it * 512 + tid;
      const float4 v = xg[e4];
      const int e = e4 << 2;
      const int r = e >> 9, k = e & 511;   // k % 4 == 0 -> inside one 8-chunk
      ushort4 pk;
      pk.x = f2bf(v.x); pk.y = f2bf(v.y); pk.z = f2bf(v.z); pk.w = f2bf(v.w);
      *(ushort4*)&x_s[xsw(r, k)] = pk;
    }
  }
  __syncthreads();

  unsigned short* ow = outu + (size_t)b * 65536;  // O16 [64][512]

  unsigned short* q_s = sc[wid];            // Qn [64][32] (qsw)
  unsigned short* k_s = sc[wid] + 2048;     // Kn [64][32] (qsw)
  unsigned short* v_slot = sc[wid] + 4096;  // V^T [32][64] (psw), then O [64][32] (qsw)
  unsigned short* p_s = sc[wid];            // P [64][64] (psw) overlays Q|K

  const f32x4 zacc = {0.f, 0.f, 0.f, 0.f};
  const float* mk = mask + (size_t)(b & 255) * 4096;

  for (int rnd = 0; rnd < 2; ++rnd) {
    const int h = rnd * 8 + wid;
    const float scale_h = __expf(fminf(logit_scale[h], 4.6051701859880914f));
    const unsigned short* wq = wqkv_t + (size_t)(h * 32) * 512;
    const unsigned short* wk = wqkv_t + (size_t)(512 + h * 32) * 512;
    const unsigned short* wv = wqkv_t + (size_t)(1024 + h * 32) * 512;

    // ---- Stage A1: Q,K = x @ Wq_h, x @ Wk_h  (256 MFMA)
    {
      f32x4 aq[4][2], ak[4][2];
#pragma unroll
      for (int mt = 0; mt < 4; ++mt)
#pragma unroll
        for (int nt = 0; nt < 2; ++nt) { aq[mt][nt] = zacc; ak[mt][nt] = zacc; }
#pragma unroll
      for (int ks = 0; ks < 16; ++ks) {
        const int k0 = ks * 32 + g * 8;
        bf16x8 A[4];
#pragma unroll
        for (int mt = 0; mt < 4; ++mt)
          A[mt] = *(const bf16x8*)&x_s[xsw(mt * 16 + c16, k0)];
#pragma unroll
        for (int nt = 0; nt < 2; ++nt) {
          const int ro = (nt * 16 + c16) * 512 + k0;
          const bf16x8 Bq = *(const bf16x8*)&wq[ro];
          const bf16x8 Bk = *(const bf16x8*)&wk[ro];
#pragma unroll
          for (int mt = 0; mt < 4; ++mt) {
            aq[mt][nt] = MFMA16(A[mt], Bq, aq[mt][nt]);
            ak[mt][nt] = MFMA16(A[mt], Bk, ak[mt][nt]);
          }
        }
      }
      const float qb0 = q_bias[h * 32 + c16];
      const float qb1 = q_bias[h * 32 + 16 + c16];
#pragma unroll
      for (int mt = 0; mt < 4; ++mt) {
#pragma unroll
        for (int j = 0; j < 4; ++j) {
          const int row = mt * 16 + g * 4 + j;  // C layout: row=(lane>>4)*4+reg
          float q0 = aq[mt][0][j] + qb0;
          float q1 = aq[mt][1][j] + qb1;
          float ss = q0 * q0 + q1 * q1;
          ss += __shfl_xor(ss, 1); ss += __shfl_xor(ss, 2);
          ss += __shfl_xor(ss, 4); ss += __shfl_xor(ss, 8);
          const float rn = scale_h * rsqrtf(ss);
          q_s[qsw(row, c16)] = f2bf(q0 * rn);
          q_s[qsw(row, 16 + c16)] = f2bf(q1 * rn);
          const float k0v = ak[mt][0][j];
          const float k1v = ak[mt][1][j];
          float sk = k0v * k0v + k1v * k1v;
          sk += __shfl_xor(sk, 1); sk += __shfl_xor(sk, 2);
          sk += __shfl_xor(sk, 4); sk += __shfl_xor(sk, 8);
          const float rk = rsqrtf(sk);
          k_s[qsw(row, c16)] = f2bf(k0v * rk);
          k_s[qsw(row, 16 + c16)] = f2bf(k1v * rk);
        }
      }
    }

    // ---- Stage A2: V = x @ Wv_h  (128 MFMA), stored transposed [d][token]
    {
      f32x4 av[4][2];
#pragma unroll
      for (int mt = 0; mt < 4; ++mt)
#pragma unroll
        for (int nt = 0; nt < 2; ++nt) av[mt][nt] = zacc;
#pragma unroll
      for (int ks = 0; ks < 16; ++ks) {
        const int k0 = ks * 32 + g * 8;
        bf16x8 A[4];
#pragma unroll
        for (int mt = 0; mt < 4; ++mt)
          A[mt] = *(const bf16x8*)&x_s[xsw(mt * 16 + c16, k0)];
#pragma unroll
        for (int nt = 0; nt < 2; ++nt) {
          const bf16x8 Bv = *(const bf16x8*)&wv[(nt * 16 + c16) * 512 + k0];
#pragma unroll
          for (int mt = 0; mt < 4; ++mt)
            av[mt][nt] = MFMA16(A[mt], Bv, av[mt][nt]);
        }
      }
      const float vb0 = v_bias[h * 32 + c16];
      const float vb1 = v_bias[h * 32 + 16 + c16];
#pragma unroll
      for (int mt = 0; mt < 4; ++mt) {
#pragma unroll
        for (int j = 0; j < 4; ++j) {
          const int row = mt * 16 + g * 4 + j;
          v_slot[psw(c16, row)] = f2bf(av[mt][0][j] + vb0);
          v_slot[psw(16 + c16, row)] = f2bf(av[mt][1][j] + vb1);
        }
      }
    }

    // ---- Stage B: S = Qn @ Kn^T (16 MFMA), + CPB bias + mask, softmax
    f32x4 S[4][4];
    {
      bf16x8 A[4], Bk4[4];
#pragma unroll
      for (int mt = 0; mt < 4; ++mt)
        A[mt] = *(const bf16x8*)&q_s[qsw(mt * 16 + c16, g * 8)];
#pragma unroll
      for (int nt = 0; nt < 4; ++nt)
        Bk4[nt] = *(const bf16x8*)&k_s[qsw(nt * 16 + c16, g * 8)];
#pragma unroll
      for (int mt = 0; mt < 4; ++mt)
#pragma unroll
        for (int nt = 0; nt < 4; ++nt)
          S[mt][nt] = MFMA16(A[mt], Bk4[nt], zacc);
    }
    const float* bt = bias_tab + (size_t)h * 4096;
#pragma unroll
    for (int mt = 0; mt < 4; ++mt)
#pragma unroll
      for (int j = 0; j < 4; ++j) {
        const int r = mt * 16 + g * 4 + j;
#pragma unroll
        for (int nt = 0; nt < 4; ++nt) {
          const int c = nt * 16 + c16;
          S[mt][nt][j] += bt[r * 64 + c] + mk[r * 64 + c];
        }
      }
#pragma unroll
    for (int mt = 0; mt < 4; ++mt)
#pragma unroll
      for (int j = 0; j < 4; ++j) {
        float m0 = fmaxf(fmaxf(S[mt][0][j], S[mt][1][j]), fmaxf(S[mt][2][j], S[mt][3][j]));
        m0 = fmaxf(m0, __shfl_xor(m0, 1));
        m0 = fmaxf(m0, __shfl_xor(m0, 2));
        m0 = fmaxf(m0, __shfl_xor(m0, 4));
        m0 = fmaxf(m0, __shfl_xor(m0, 8));
        float sum = 0.f;
#pragma unroll
        for (int nt = 0; nt < 4; ++nt) {
          const float p = __expf(S[mt][nt][j] - m0);
          S[mt][nt][j] = p;
          sum += p;
        }
        sum += __shfl_xor(sum, 1); sum += __shfl_xor(sum, 2);
        sum += __shfl_xor(sum, 4); sum += __shfl_xor(sum, 8);
        const float inv = 1.f / sum;
        const int r = mt * 16 + g * 4 + j;
#pragma unroll
        for (int nt = 0; nt < 4; ++nt)
          p_s[psw(r, nt * 16 + c16)] = f2bf(S[mt][nt][j] * inv);
      }

    // ---- Stage C: O = P @ V (16 MFMA), O -> v_slot (V^T dead after reads)
    f32x4 O[4][2];
#pragma unroll
    for (int mt = 0; mt < 4; ++mt)
#pragma unroll
      for (int nt = 0; nt < 2; ++nt) O[mt][nt] = zacc;
#pragma unroll
    for (int ks = 0; ks < 2; ++ks) {
      bf16x8 A[4], B2[2];
#pragma unroll
      for (int mt = 0; mt < 4; ++mt)
        A[mt] = *(const bf16x8*)&p_s[psw(mt * 16 + c16, ks * 32 + g * 8)];
#pragma unroll
      for (int nt = 0; nt < 2; ++nt)
        B2[nt] = *(const bf16x8*)&v_slot[psw(nt * 16 + c16, ks * 32 + g * 8)];
#pragma unroll
      for (int mt = 0; mt < 4; ++mt)
#pragma unroll
        for (int nt = 0; nt < 2; ++nt)
          O[mt][nt] = MFMA16(A[mt], B2[nt], O[mt][nt]);
    }
#pragma unroll
    for (int mt = 0; mt < 4; ++mt)
#pragma unroll
      for (int j = 0; j < 4; ++j) {
        const int row = mt * 16 + g * 4 + j;
        v_slot[qsw(row, c16)] = f2bf(O[mt][0][j]);
        v_slot[qsw(row, 16 + c16)] = f2bf(O[mt][1][j]);
      }

    // ---- O store: wave-private LDS -> global, 8 B per lane per iter
#pragma unroll
    for (int i = 0; i < 8; ++i) {
      const int chunk = i * 64 + lane;
      const int r = chunk >> 3;
      const int c4 = (chunk & 7) << 2;
      const ushort4 v = *(const ushort4*)&v_slot[qsw(r, c4)];
      *(ushort4*)&ow[r * 512 + h * 32 + c4] = v;
    }
  }
}

// ---------------------------------------------------------------- proj_gemm
// Per window: stage O16 [64][512] -> LDS (xsw), then out = O @ proj_t + b,
// overwriting the window region with f32. 4 waves, each does two 64-col strips.
__global__ __launch_bounds__(256, 2) void proj_gemm(
    const unsigned short* __restrict__ proj_t,
    const float* __restrict__ proj_b,
    float* __restrict__ out) {
  __shared__ __align__(16) unsigned short o_s[64 * 512];  // 64 KB

  const int tid = threadIdx.x;
  const int wid = tid >> 6;
  const int lane = tid & 63;
  const int c16 = lane & 15;
  const int g = lane >> 4;
  const int b = blockIdx.x;

  const unsigned short* ow = (const unsigned short*)out + (size_t)b * 65536;
  float* og = out + (size_t)b * 32768;

  // stage O16 -> LDS swizzled: 4096 chunks of 8 ushorts (full 64x512 tile)
#pragma unroll
  for (int i = 0; i < 16; ++i) {
    const int ch = i * 256 + tid;          // 8-ushort chunk id, 4096 total
    const int r = ch >> 6;                 // 64 chunks of 8 per row
    const int k = (ch & 63) << 3;
    const ushort4 lo = *(const ushort4*)&ow[ch * 8];
    const ushort4 hi = *(const ushort4*)&ow[ch * 8 + 4];
    *(ushort4*)&o_s[xsw(r, k)] = lo;
    *(ushort4*)&o_s[xsw(r, k) + 4] = hi;
  }
  __syncthreads();

  const f32x4 zacc = {0.f, 0.f, 0.f, 0.f};
#pragma unroll
  for (int half = 0; half < 2; ++half) {
    const int c0 = half * 256 + wid * 64;
    f32x4 outacc[4][4];
#pragma unroll
    for (int mt = 0; mt < 4; ++mt)
#pragma unroll
      for (int nt = 0; nt < 4; ++nt) outacc[mt][nt] = zacc;
#pragma unroll
    for (int ks = 0; ks < 16; ++ks) {
      const int k0 = ks * 32 + g * 8;
      bf16x8 A[4];
#pragma unroll
      for (int mt = 0; mt < 4; ++mt)
        A[mt] = *(const bf16x8*)&o_s[xsw(mt * 16 + c16, k0)];
#pragma unroll
      for (int nt = 0; nt < 4; ++nt) {
        const bf16x8 Bf = *(const bf16x8*)&proj_t[(size_t)(c0 + nt * 16 + c16) * 512 + k0];
#pragma unroll
        for (int mt = 0; mt < 4; ++mt)
          outacc[mt][nt] = MFMA16(A[mt], Bf, outacc[mt][nt]);
      }
    }
    // f32 writes clobber O16 bytes, but all O reads come from LDS -> safe.
#pragma unroll
    for (int nt = 0; nt < 4; ++nt) {
      const int c = c0 + nt * 16 + c16;
      const float pb = proj_b[c];
#pragma unroll
      for (int mt = 0; mt < 4; ++mt) {
#pragma unroll
        for (int j = 0; j < 4; ++j) {
          const int r = mt * 16 + g * 4 + j;
          og[r * 512 + c] = outacc[mt][nt][j] + pb;
        }
      }
    }
  }
}

// ---------------------------------------------------------------- launch
extern "C" void kernel_launch(void* const* d_in, const int* in_sizes, int n_in,
                              void* d_out, int out_size, void* d_ws, size_t ws_size,
                              hipStream_t stream) {
  const float* x = (const float*)d_in[0];
  const float* mask = (const float*)d_in[1];
  const float* rel_table = (const float*)d_in[2];
  const float* w_qkv = (const float*)d_in[3];
  const float* q_bias = (const float*)d_in[4];
  const float* v_bias = (const float*)d_in[5];
  const float* logit_scale = (const float*)d_in[6];
  const float* cpb_w1 = (const float*)d_in[7];
  const float* cpb_b1 = (const float*)d_in[8];
  const float* cpb_w2 = (const float*)d_in[9];
  const float* proj_w = (const float*)d_in[10];
  const float* proj_b = (const float*)d_in[11];

  char* ws = (char*)d_ws;
  float* bias_tab = (float*)(ws);
  unsigned short* wqkv_t = (unsigned short*)(ws + 262144);
  unsigned short* proj_t = (unsigned short*)(ws + 262144 + 1572864);
  float* tab225 = (float*)(ws + 262144 + 1572864 + 524288);

  unsigned short* outu = (unsigned short*)d_out;

  prep1<<<2273, 256, 0, stream>>>(rel_table, w_qkv, proj_w, cpb_w1, cpb_b1, cpb_w2,
                                  wqkv_t, proj_t, tab225);
  prep2<<<16, 256, 0, stream>>>(tab225, bias_tab);
  win_attn<<<2048, 512, 0, stream>>>(x, mask, q_bias, v_bias, logit_scale,
                                     wqkv_t, bias_tab, outu);
  proj_gemm<<<2048, 256, 0, stream>>>(proj_t, proj_b, (float*)d_out);
}

// Round 6
// 1878.000 us; speedup vs baseline: 1.6632x; 1.2073x over previous
//
#include <hip/hip_runtime.h>
#include <hip/hip_bf16.h>

// Swin-V2 window attention. B=2048 windows, N=64 tokens, CH=512, H=16 heads,
// d=32, NW=256 masks. bf16 MFMA 16x16x32, f32 accumulation.
//
// Round-6: eliminate spills under the empirical 128-VGPR cap for 512-thread
// blocks (observed: 8-wave kernels allocate 128 VGPRs regardless of
// __launch_bounds__ second arg; R5's Stage A1 needed ~130+ -> ~950 MB
// symmetric scratch traffic = the whole remaining overhead). Stage A is now
// THREE passes (Q, K, V), each holding only a 4x2 f32x4 accumulator (32
// VGPRs) + frags -> peak live ~85 regs. x_s A-frags re-read from LDS per
// pass (LDS BW is free at this scale).
//
//   win_attn:  8 waves, wave = 1 head x 2 rounds; x staged f32->bf16 to LDS
//              once (single barrier); writes O bf16 into d_out's per-window
//              1st half (64 KB of 128).
//   proj_gemm: stages O16 -> LDS (swizzled), then overwrites window with f32.
//
// ws layout (2.38 MB):
//   [0)        bias_tab f32 [16][64][64]   = 262144 B
//   [262144)   wqkv_t  bf16 [1536][512]    = 1572864 B  (w_qkv^T, n-major)
//   [1835008)  proj_t  bf16 [512][512]    = 524288 B   (proj_w^T, n-major)
//   [2359296)  tab225  f32 [225][16]      = 14400 B

typedef __attribute__((ext_vector_type(4))) float f32x4;
typedef __attribute__((ext_vector_type(8))) __bf16 bf16x8;

#define MFMA16(a, b, c) __builtin_amdgcn_mfma_f32_16x16x32_bf16((a), (b), (c), 0, 0, 0)

__device__ __forceinline__ unsigned short f2bf(float f) {
  union { float f; unsigned u; } v; v.f = f;
  unsigned r = v.u + 0x7fffu + ((v.u >> 16) & 1u);   // round-to-nearest-even
  return (unsigned short)(r >> 16);
}

// ---- swizzled LDS element-index helpers (same map on write and read) ----
// [.][512] rows: permute 16B chunks within row by row&7.
__device__ __forceinline__ int xsw(int r, int k) {
  return r * 512 + ((((k >> 3) ^ (r & 7)) << 3) | (k & 7));
}
// 32-col slots (Qn/Kn/O) [64][32].
__device__ __forceinline__ int qsw(int r, int c) {
  return r * 32 + ((((c >> 3) ^ ((r >> 1) & 3)) << 3) | (c & 7));
}
// 64-col slots (V^T [32][64], P [64][64]).
__device__ __forceinline__ int psw(int r, int c) {
  return r * 64 + ((((c >> 3) ^ (r & 7)) << 3) | (c & 7));
}

// ---------------------------------------------------------------- prep1
__global__ void prep1(const float* __restrict__ rel_table,
                      const float* __restrict__ w_qkv,
                      const float* __restrict__ proj_w,
                      const float* __restrict__ cpb_w1,
                      const float* __restrict__ cpb_b1,
                      const float* __restrict__ cpb_w2,
                      unsigned short* __restrict__ wqkv_t,
                      unsigned short* __restrict__ proj_t,
                      float* __restrict__ tab225) {
  const int bid = blockIdx.x, tid = threadIdx.x;
  __shared__ float red[4][16];
  if (bid < 225) {
    const float t0 = rel_table[bid * 2], t1 = rel_table[bid * 2 + 1];
    float acc[16];
#pragma unroll
    for (int h = 0; h < 16; ++h) acc[h] = 0.f;
    for (int j = tid; j < 512; j += 256) {
      const float hj = fmaxf(t0 * cpb_w1[j] + t1 * cpb_w1[512 + j] + cpb_b1[j], 0.f);
#pragma unroll
      for (int h = 0; h < 16; ++h) acc[h] += hj * cpb_w2[j * 16 + h];
    }
    const int lane = tid & 63, w = tid >> 6;
#pragma unroll
    for (int h = 0; h < 16; ++h) {
      float v = acc[h];
      for (int m = 1; m < 64; m <<= 1) v += __shfl_xor(v, m);
      if (lane == 0) red[w][h] = v;
    }
    __syncthreads();
    if (tid < 16)
      tab225[bid * 16 + tid] = red[0][tid] + red[1][tid] + red[2][tid] + red[3][tid];
  } else if (bid < 225 + 1536) {
    const int n = bid - 225;
    for (int k = tid; k < 512; k += 256)
      wqkv_t[n * 512 + k] = f2bf(w_qkv[(size_t)k * 1536 + n]);
  } else {
    const int n = bid - 1761;
    for (int k = tid; k < 512; k += 256)
      proj_t[n * 512 + k] = f2bf(proj_w[(size_t)k * 512 + n]);
  }
}

// ---------------------------------------------------------------- prep2
__global__ void prep2(const float* __restrict__ tab225, float* __restrict__ bias_tab) {
  const int h = blockIdx.x, tid = threadIdx.x;
  for (int e = tid; e < 4096; e += 256) {
    const int n = e >> 6, m = e & 63;
    const int dr = (n >> 3) - (m >> 3) + 7;
    const int dc = (n & 7) - (m & 7) + 7;
    const float v = tab225[(dr * 15 + dc) * 16 + h];
    bias_tab[h * 4096 + e] = 16.f / (1.f + __expf(-v));
  }
}

// ---------------------------------------------------------------- win_attn
__global__ __launch_bounds__(512) void win_attn(
    const float* __restrict__ x,
    const float* __restrict__ mask,
    const float* __restrict__ q_bias,
    const float* __restrict__ v_bias,
    const float* __restrict__ logit_scale,
    const unsigned short* __restrict__ wqkv_t,
    const float* __restrict__ bias_tab,
    unsigned short* __restrict__ outu) {
  __shared__ __align__(16) unsigned short x_s[64 * 512];    // 65536 B (xsw)
  __shared__ __align__(16) unsigned short sc[8][3 * 2048];  // 98304 B wave scratch

  const int tid = threadIdx.x;
  const int wid = tid >> 6;     // 0..7
  const int lane = tid & 63;
  const int c16 = lane & 15;
  const int g = lane >> 4;
  const int b = blockIdx.x;

  // Phase 0: stage x window f32 -> bf16 into swizzled LDS (coalesced float4).
  {
    const float4* xg = (const float4*)(x + (size_t)b * (64 * 512));
#pragma unroll
    for (int it = 0; it < 16; ++it) {
      const int e4 = it * 512 + tid;
      const float4 v = xg[e4];
      const int e = e4 << 2;
      const int r = e >> 9, k = e & 511;
      ushort4 pk;
      pk.x = f2bf(v.x); pk.y = f2bf(v.y); pk.z = f2bf(v.z); pk.w = f2bf(v.w);
      *(ushort4*)&x_s[xsw(r, k)] = pk;
    }
  }
  __syncthreads();

  unsigned short* ow = outu + (size_t)b * 65536;  // O16 [64][512]

  unsigned short* q_s = sc[wid];            // Qn [64][32] (qsw)
  unsigned short* k_s = sc[wid] + 2048;     // Kn [64][32] (qsw)
  unsigned short* v_slot = sc[wid] + 4096;  // V^T [32][64] (psw), then O [64][32] (qsw)
  unsigned short* p_s = sc[wid];            // P [64][64] (psw) overlays Q|K

  const f32x4 zacc = {0.f, 0.f, 0.f, 0.f};
  const float* mk = mask + (size_t)(b & 255) * 4096;

  for (int rnd = 0; rnd < 2; ++rnd) {
    const int h = rnd * 8 + wid;
    const float scale_h = __expf(fminf(logit_scale[h], 4.6051701859880914f));

    // ---- Pass Q: Q[64,32] = x @ Wq_h (128 MFMA), normalize*scale, -> q_s
    {
      const unsigned short* wq = wqkv_t + (size_t)(h * 32) * 512;
      f32x4 acc[4][2];
#pragma unroll
      for (int mt = 0; mt < 4; ++mt)
#pragma unroll
        for (int nt = 0; nt < 2; ++nt) acc[mt][nt] = zacc;
#pragma unroll
      for (int ks = 0; ks < 16; ++ks) {
        const int k0 = ks * 32 + g * 8;
        bf16x8 A[4];
#pragma unroll
        for (int mt = 0; mt < 4; ++mt)
          A[mt] = *(const bf16x8*)&x_s[xsw(mt * 16 + c16, k0)];
#pragma unroll
        for (int nt = 0; nt < 2; ++nt) {
          const bf16x8 Bq = *(const bf16x8*)&wq[(nt * 16 + c16) * 512 + k0];
#pragma unroll
          for (int mt = 0; mt < 4; ++mt)
            acc[mt][nt] = MFMA16(A[mt], Bq, acc[mt][nt]);
        }
      }
      const float qb0 = q_bias[h * 32 + c16];
      const float qb1 = q_bias[h * 32 + 16 + c16];
#pragma unroll
      for (int mt = 0; mt < 4; ++mt) {
#pragma unroll
        for (int j = 0; j < 4; ++j) {
          const int row = mt * 16 + g * 4 + j;  // C layout: row=(lane>>4)*4+reg
          float q0 = acc[mt][0][j] + qb0;
          float q1 = acc[mt][1][j] + qb1;
          float ss = q0 * q0 + q1 * q1;
          ss += __shfl_xor(ss, 1); ss += __shfl_xor(ss, 2);
          ss += __shfl_xor(ss, 4); ss += __shfl_xor(ss, 8);
          const float rn = scale_h * rsqrtf(ss);
          q_s[qsw(row, c16)] = f2bf(q0 * rn);
          q_s[qsw(row, 16 + c16)] = f2bf(q1 * rn);
        }
      }
    }

    // ---- Pass K: K[64,32] = x @ Wk_h (128 MFMA), normalize, -> k_s
    {
      const unsigned short* wk = wqkv_t + (size_t)(512 + h * 32) * 512;
      f32x4 acc[4][2];
#pragma unroll
      for (int mt = 0; mt < 4; ++mt)
#pragma unroll
        for (int nt = 0; nt < 2; ++nt) acc[mt][nt] = zacc;
#pragma unroll
      for (int ks = 0; ks < 16; ++ks) {
        const int k0 = ks * 32 + g * 8;
        bf16x8 A[4];
#pragma unroll
        for (int mt = 0; mt < 4; ++mt)
          A[mt] = *(const bf16x8*)&x_s[xsw(mt * 16 + c16, k0)];
#pragma unroll
        for (int nt = 0; nt < 2; ++nt) {
          const bf16x8 Bk = *(const bf16x8*)&wk[(nt * 16 + c16) * 512 + k0];
#pragma unroll
          for (int mt = 0; mt < 4; ++mt)
            acc[mt][nt] = MFMA16(A[mt], Bk, acc[mt][nt]);
        }
      }
#pragma unroll
      for (int mt = 0; mt < 4; ++mt) {
#pragma unroll
        for (int j = 0; j < 4; ++j) {
          const int row = mt * 16 + g * 4 + j;
          const float k0v = acc[mt][0][j];
          const float k1v = acc[mt][1][j];
          float sk = k0v * k0v + k1v * k1v;
          sk += __shfl_xor(sk, 1); sk += __shfl_xor(sk, 2);
          sk += __shfl_xor(sk, 4); sk += __shfl_xor(sk, 8);
          const float rk = rsqrtf(sk);
          k_s[qsw(row, c16)] = f2bf(k0v * rk);
          k_s[qsw(row, 16 + c16)] = f2bf(k1v * rk);
        }
      }
    }

    // ---- Pass V: V[64,32] = x @ Wv_h (128 MFMA), stored transposed [d][token]
    {
      const unsigned short* wv = wqkv_t + (size_t)(1024 + h * 32) * 512;
      f32x4 acc[4][2];
#pragma unroll
      for (int mt = 0; mt < 4; ++mt)
#pragma unroll
        for (int nt = 0; nt < 2; ++nt) acc[mt][nt] = zacc;
#pragma unroll
      for (int ks = 0; ks < 16; ++ks) {
        const int k0 = ks * 32 + g * 8;
        bf16x8 A[4];
#pragma unroll
        for (int mt = 0; mt < 4; ++mt)
          A[mt] = *(const bf16x8*)&x_s[xsw(mt * 16 + c16, k0)];
#pragma unroll
        for (int nt = 0; nt < 2; ++nt) {
          const bf16x8 Bv = *(const bf16x8*)&wv[(nt * 16 + c16) * 512 + k0];
#pragma unroll
          for (int mt = 0; mt < 4; ++mt)
            acc[mt][nt] = MFMA16(A[mt], Bv, acc[mt][nt]);
        }
      }
      const float vb0 = v_bias[h * 32 + c16];
      const float vb1 = v_bias[h * 32 + 16 + c16];
#pragma unroll
      for (int mt = 0; mt < 4; ++mt) {
#pragma unroll
        for (int j = 0; j < 4; ++j) {
          const int row = mt * 16 + g * 4 + j;
          v_slot[psw(c16, row)] = f2bf(acc[mt][0][j] + vb0);
          v_slot[psw(16 + c16, row)] = f2bf(acc[mt][1][j] + vb1);
        }
      }
    }

    // ---- Stage B: S = Qn @ Kn^T (16 MFMA), + CPB bias + mask, softmax
    f32x4 S[4][4];
    {
      bf16x8 A[4], Bk4[4];
#pragma unroll
      for (int mt = 0; mt < 4; ++mt)
        A[mt] = *(const bf16x8*)&q_s[qsw(mt * 16 + c16, g * 8)];
#pragma unroll
      for (int nt = 0; nt < 4; ++nt)
        Bk4[nt] = *(const bf16x8*)&k_s[qsw(nt * 16 + c16, g * 8)];
#pragma unroll
      for (int mt = 0; mt < 4; ++mt)
#pragma unroll
        for (int nt = 0; nt < 4; ++nt)
          S[mt][nt] = MFMA16(A[mt], Bk4[nt], zacc);
    }
    const float* bt = bias_tab + (size_t)h * 4096;
#pragma unroll
    for (int mt = 0; mt < 4; ++mt)
#pragma unroll
      for (int j = 0; j < 4; ++j) {
        const int r = mt * 16 + g * 4 + j;
#pragma unroll
        for (int nt = 0; nt < 4; ++nt) {
          const int c = nt * 16 + c16;
          S[mt][nt][j] += bt[r * 64 + c] + mk[r * 64 + c];
        }
      }
#pragma unroll
    for (int mt = 0; mt < 4; ++mt)
#pragma unroll
      for (int j = 0; j < 4; ++j) {
        float m0 = fmaxf(fmaxf(S[mt][0][j], S[mt][1][j]), fmaxf(S[mt][2][j], S[mt][3][j]));
        m0 = fmaxf(m0, __shfl_xor(m0, 1));
        m0 = fmaxf(m0, __shfl_xor(m0, 2));
        m0 = fmaxf(m0, __shfl_xor(m0, 4));
        m0 = fmaxf(m0, __shfl_xor(m0, 8));
        float sum = 0.f;
#pragma unroll
        for (int nt = 0; nt < 4; ++nt) {
          const float p = __expf(S[mt][nt][j] - m0);
          S[mt][nt][j] = p;
          sum += p;
        }
        sum += __shfl_xor(sum, 1); sum += __shfl_xor(sum, 2);
        sum += __shfl_xor(sum, 4); sum += __shfl_xor(sum, 8);
        const float inv = 1.f / sum;
        const int r = mt * 16 + g * 4 + j;
#pragma unroll
        for (int nt = 0; nt < 4; ++nt)
          p_s[psw(r, nt * 16 + c16)] = f2bf(S[mt][nt][j] * inv);
      }

    // ---- Stage C: O = P @ V (16 MFMA), O -> v_slot (V^T dead after reads)
    f32x4 O[4][2];
#pragma unroll
    for (int mt = 0; mt < 4; ++mt)
#pragma unroll
      for (int nt = 0; nt < 2; ++nt) O[mt][nt] = zacc;
#pragma unroll
    for (int ks = 0; ks < 2; ++ks) {
      bf16x8 A[4], B2[2];
#pragma unroll
      for (int mt = 0; mt < 4; ++mt)
        A[mt] = *(const bf16x8*)&p_s[psw(mt * 16 + c16, ks * 32 + g * 8)];
#pragma unroll
      for (int nt = 0; nt < 2; ++nt)
        B2[nt] = *(const bf16x8*)&v_slot[psw(nt * 16 + c16, ks * 32 + g * 8)];
#pragma unroll
      for (int mt = 0; mt < 4; ++mt)
#pragma unroll
        for (int nt = 0; nt < 2; ++nt)
          O[mt][nt] = MFMA16(A[mt], B2[nt], O[mt][nt]);
    }
#pragma unroll
    for (int mt = 0; mt < 4; ++mt)
#pragma unroll
      for (int j = 0; j < 4; ++j) {
        const int row = mt * 16 + g * 4 + j;
        v_slot[qsw(row, c16)] = f2bf(O[mt][0][j]);
        v_slot[qsw(row, 16 + c16)] = f2bf(O[mt][1][j]);
      }

    // ---- O store: wave-private LDS -> global, 8 B per lane per iter
#pragma unroll
    for (int i = 0; i < 8; ++i) {
      const int chunk = i * 64 + lane;
      const int r = chunk >> 3;
      const int c4 = (chunk & 7) << 2;
      const ushort4 v = *(const ushort4*)&v_slot[qsw(r, c4)];
      *(ushort4*)&ow[r * 512 + h * 32 + c4] = v;
    }
  }
}

// ---------------------------------------------------------------- proj_gemm
// Per window: stage O16 [64][512] -> LDS (xsw), then out = O @ proj_t + b,
// overwriting the window region with f32. 4 waves, each does two 64-col strips.
__global__ __launch_bounds__(256, 2) void proj_gemm(
    const unsigned short* __restrict__ proj_t,
    const float* __restrict__ proj_b,
    float* __restrict__ out) {
  __shared__ __align__(16) unsigned short o_s[64 * 512];  // 64 KB

  const int tid = threadIdx.x;
  const int wid = tid >> 6;
  const int lane = tid & 63;
  const int c16 = lane & 15;
  const int g = lane >> 4;
  const int b = blockIdx.x;

  const unsigned short* ow = (const unsigned short*)out + (size_t)b * 65536;
  float* og = out + (size_t)b * 32768;

  // stage O16 -> LDS swizzled: 4096 chunks of 8 ushorts (full 64x512 tile)
#pragma unroll
  for (int i = 0; i < 16; ++i) {
    const int ch = i * 256 + tid;          // 8-ushort chunk id, 4096 total
    const int r = ch >> 6;                 // 64 chunks of 8 per row
    const int k = (ch & 63) << 3;
    const ushort4 lo = *(const ushort4*)&ow[ch * 8];
    const ushort4 hi = *(const ushort4*)&ow[ch * 8 + 4];
    *(ushort4*)&o_s[xsw(r, k)] = lo;
    *(ushort4*)&o_s[xsw(r, k) + 4] = hi;
  }
  __syncthreads();

  const f32x4 zacc = {0.f, 0.f, 0.f, 0.f};
#pragma unroll
  for (int half = 0; half < 2; ++half) {
    const int c0 = half * 256 + wid * 64;
    f32x4 outacc[4][4];
#pragma unroll
    for (int mt = 0; mt < 4; ++mt)
#pragma unroll
      for (int nt = 0; nt < 4; ++nt) outacc[mt][nt] = zacc;
#pragma unroll
    for (int ks = 0; ks < 16; ++ks) {
      const int k0 = ks * 32 + g * 8;
      bf16x8 A[4];
#pragma unroll
      for (int mt = 0; mt < 4; ++mt)
        A[mt] = *(const bf16x8*)&o_s[xsw(mt * 16 + c16, k0)];
#pragma unroll
      for (int nt = 0; nt < 4; ++nt) {
        const bf16x8 Bf = *(const bf16x8*)&proj_t[(size_t)(c0 + nt * 16 + c16) * 512 + k0];
#pragma unroll
        for (int mt = 0; mt < 4; ++mt)
          outacc[mt][nt] = MFMA16(A[mt], Bf, outacc[mt][nt]);
      }
    }
    // f32 writes clobber O16 bytes, but all O reads come from LDS -> safe.
#pragma unroll
    for (int nt = 0; nt < 4; ++nt) {
      const int c = c0 + nt * 16 + c16;
      const float pb = proj_b[c];
#pragma unroll
      for (int mt = 0; mt < 4; ++mt) {
#pragma unroll
        for (int j = 0; j < 4; ++j) {
          const int r = mt * 16 + g * 4 + j;
          og[r * 512 + c] = outacc[mt][nt][j] + pb;
        }
      }
    }
  }
}

// ---------------------------------------------------------------- launch
extern "C" void kernel_launch(void* const* d_in, const int* in_sizes, int n_in,
                              void* d_out, int out_size, void* d_ws, size_t ws_size,
                              hipStream_t stream) {
  const float* x = (const float*)d_in[0];
  const float* mask = (const float*)d_in[1];
  const float* rel_table = (const float*)d_in[2];
  const float* w_qkv = (const float*)d_in[3];
  const float* q_bias = (const float*)d_in[4];
  const float* v_bias = (const float*)d_in[5];
  const float* logit_scale = (const float*)d_in[6];
  const float* cpb_w1 = (const float*)d_in[7];
  const float* cpb_b1 = (const float*)d_in[8];
  const float* cpb_w2 = (const float*)d_in[9];
  const float* proj_w = (const float*)d_in[10];
  const float* proj_b = (const float*)d_in[11];

  char* ws = (char*)d_ws;
  float* bias_tab = (float*)(ws);
  unsigned short* wqkv_t = (unsigned short*)(ws + 262144);
  unsigned short* proj_t = (unsigned short*)(ws + 262144 + 1572864);
  float* tab225 = (float*)(ws + 262144 + 1572864 + 524288);

  unsigned short* outu = (unsigned short*)d_out;

  prep1<<<2273, 256, 0, stream>>>(rel_table, w_qkv, proj_w, cpb_w1, cpb_b1, cpb_w2,
                                  wqkv_t, proj_t, tab225);
  prep2<<<16, 256, 0, stream>>>(tab225, bias_tab);
  win_attn<<<2048, 512, 0, stream>>>(x, mask, q_bias, v_bias, logit_scale,
                                     wqkv_t, bias_tab, outu);
  proj_gemm<<<2048, 256, 0, stream>>>(proj_t, proj_b, (float*)d_out);
}

// Round 7
// 1798.793 us; speedup vs baseline: 1.7364x; 1.0440x over previous
//
#include <hip/hip_runtime.h>
#include <hip/hip_bf16.h>

// Swin-V2 window attention. B=2048 windows, N=64 tokens, CH=512, H=16 heads,
// d=32, NW=256 masks. bf16 MFMA 16x16x32, f32 accumulation.
//
// Round-7: kill the last spill site. R6 left ~500 MB symmetric HBM excess
// (~120 f32/thread): Stage B held S[4][4] (64 regs) + frags (32) + 32 scalar
// bias/mask loads under the 128-VGPR cap -> ~60 regs spilled per round.
// Stage B is now per-row-tile (mt): S[4] (16 regs) at a time, softmax per
// tile. A4/Bk4 frags prefetched BEFORE any P write (P overlays q_s/k_s).
// Peak Stage-B live ~70 regs. Everything else identical to R6.
//
//   win_attn:  8 waves / 512 thr, wave = 1 head x 2 rounds; x staged
//              f32->bf16 to LDS once (single barrier); writes O bf16 into
//              d_out's per-window 1st half (64 KB of 128).
//   proj_gemm: stages O16 -> LDS (swizzled), then overwrites window with f32.
//
// ws layout (2.38 MB):
//   [0)        bias_tab f32 [16][64][64]   = 262144 B
//   [262144)   wqkv_t  bf16 [1536][512]    = 1572864 B  (w_qkv^T, n-major)
//   [1835008)  proj_t  bf16 [512][512]    = 524288 B   (proj_w^T, n-major)
//   [2359296)  tab225  f32 [225][16]      = 14400 B

typedef __attribute__((ext_vector_type(4))) float f32x4;
typedef __attribute__((ext_vector_type(8))) __bf16 bf16x8;

#define MFMA16(a, b, c) __builtin_amdgcn_mfma_f32_16x16x32_bf16((a), (b), (c), 0, 0, 0)

__device__ __forceinline__ unsigned short f2bf(float f) {
  union { float f; unsigned u; } v; v.f = f;
  unsigned r = v.u + 0x7fffu + ((v.u >> 16) & 1u);   // round-to-nearest-even
  return (unsigned short)(r >> 16);
}

// ---- swizzled LDS element-index helpers (same map on write and read) ----
// [.][512] rows: permute 16B chunks within row by row&7.
__device__ __forceinline__ int xsw(int r, int k) {
  return r * 512 + ((((k >> 3) ^ (r & 7)) << 3) | (k & 7));
}
// 32-col slots (Qn/Kn/O) [64][32].
__device__ __forceinline__ int qsw(int r, int c) {
  return r * 32 + ((((c >> 3) ^ ((r >> 1) & 3)) << 3) | (c & 7));
}
// 64-col slots (V^T [32][64], P [64][64]).
__device__ __forceinline__ int psw(int r, int c) {
  return r * 64 + ((((c >> 3) ^ (r & 7)) << 3) | (c & 7));
}

// ---------------------------------------------------------------- prep1
__global__ void prep1(const float* __restrict__ rel_table,
                      const float* __restrict__ w_qkv,
                      const float* __restrict__ proj_w,
                      const float* __restrict__ cpb_w1,
                      const float* __restrict__ cpb_b1,
                      const float* __restrict__ cpb_w2,
                      unsigned short* __restrict__ wqkv_t,
                      unsigned short* __restrict__ proj_t,
                      float* __restrict__ tab225) {
  const int bid = blockIdx.x, tid = threadIdx.x;
  __shared__ float red[4][16];
  if (bid < 225) {
    const float t0 = rel_table[bid * 2], t1 = rel_table[bid * 2 + 1];
    float acc[16];
#pragma unroll
    for (int h = 0; h < 16; ++h) acc[h] = 0.f;
    for (int j = tid; j < 512; j += 256) {
      const float hj = fmaxf(t0 * cpb_w1[j] + t1 * cpb_w1[512 + j] + cpb_b1[j], 0.f);
#pragma unroll
      for (int h = 0; h < 16; ++h) acc[h] += hj * cpb_w2[j * 16 + h];
    }
    const int lane = tid & 63, w = tid >> 6;
#pragma unroll
    for (int h = 0; h < 16; ++h) {
      float v = acc[h];
      for (int m = 1; m < 64; m <<= 1) v += __shfl_xor(v, m);
      if (lane == 0) red[w][h] = v;
    }
    __syncthreads();
    if (tid < 16)
      tab225[bid * 16 + tid] = red[0][tid] + red[1][tid] + red[2][tid] + red[3][tid];
  } else if (bid < 225 + 1536) {
    const int n = bid - 225;
    for (int k = tid; k < 512; k += 256)
      wqkv_t[n * 512 + k] = f2bf(w_qkv[(size_t)k * 1536 + n]);
  } else {
    const int n = bid - 1761;
    for (int k = tid; k < 512; k += 256)
      proj_t[n * 512 + k] = f2bf(proj_w[(size_t)k * 512 + n]);
  }
}

// ---------------------------------------------------------------- prep2
__global__ void prep2(const float* __restrict__ tab225, float* __restrict__ bias_tab) {
  const int h = blockIdx.x, tid = threadIdx.x;
  for (int e = tid; e < 4096; e += 256) {
    const int n = e >> 6, m = e & 63;
    const int dr = (n >> 3) - (m >> 3) + 7;
    const int dc = (n & 7) - (m & 7) + 7;
    const float v = tab225[(dr * 15 + dc) * 16 + h];
    bias_tab[h * 4096 + e] = 16.f / (1.f + __expf(-v));
  }
}

// ---------------------------------------------------------------- win_attn
__global__ __launch_bounds__(512) void win_attn(
    const float* __restrict__ x,
    const float* __restrict__ mask,
    const float* __restrict__ q_bias,
    const float* __restrict__ v_bias,
    const float* __restrict__ logit_scale,
    const unsigned short* __restrict__ wqkv_t,
    const float* __restrict__ bias_tab,
    unsigned short* __restrict__ outu) {
  __shared__ __align__(16) unsigned short x_s[64 * 512];    // 65536 B (xsw)
  __shared__ __align__(16) unsigned short sc[8][3 * 2048];  // 98304 B wave scratch

  const int tid = threadIdx.x;
  const int wid = tid >> 6;     // 0..7
  const int lane = tid & 63;
  const int c16 = lane & 15;
  const int g = lane >> 4;
  const int b = blockIdx.x;

  // Phase 0: stage x window f32 -> bf16 into swizzled LDS (coalesced float4).
  {
    const float4* xg = (const float4*)(x + (size_t)b * (64 * 512));
#pragma unroll
    for (int it = 0; it < 16; ++it) {
      const int e4 = it * 512 + tid;
      const float4 v = xg[e4];
      const int e = e4 << 2;
      const int r = e >> 9, k = e & 511;
      ushort4 pk;
      pk.x = f2bf(v.x); pk.y = f2bf(v.y); pk.z = f2bf(v.z); pk.w = f2bf(v.w);
      *(ushort4*)&x_s[xsw(r, k)] = pk;
    }
  }
  __syncthreads();

  unsigned short* ow = outu + (size_t)b * 65536;  // O16 [64][512]

  unsigned short* q_s = sc[wid];            // Qn [64][32] (qsw)
  unsigned short* k_s = sc[wid] + 2048;     // Kn [64][32] (qsw)
  unsigned short* v_slot = sc[wid] + 4096;  // V^T [32][64] (psw), then O [64][32] (qsw)
  unsigned short* p_s = sc[wid];            // P [64][64] (psw) overlays Q|K

  const f32x4 zacc = {0.f, 0.f, 0.f, 0.f};
  const float* mk = mask + (size_t)(b & 255) * 4096;

  for (int rnd = 0; rnd < 2; ++rnd) {
    const int h = rnd * 8 + wid;
    const float scale_h = __expf(fminf(logit_scale[h], 4.6051701859880914f));

    // ---- Pass Q: Q[64,32] = x @ Wq_h (128 MFMA), normalize*scale, -> q_s
    {
      const unsigned short* wq = wqkv_t + (size_t)(h * 32) * 512;
      f32x4 acc[4][2];
#pragma unroll
      for (int mt = 0; mt < 4; ++mt)
#pragma unroll
        for (int nt = 0; nt < 2; ++nt) acc[mt][nt] = zacc;
#pragma unroll
      for (int ks = 0; ks < 16; ++ks) {
        const int k0 = ks * 32 + g * 8;
        bf16x8 A[4];
#pragma unroll
        for (int mt = 0; mt < 4; ++mt)
          A[mt] = *(const bf16x8*)&x_s[xsw(mt * 16 + c16, k0)];
#pragma unroll
        for (int nt = 0; nt < 2; ++nt) {
          const bf16x8 Bq = *(const bf16x8*)&wq[(nt * 16 + c16) * 512 + k0];
#pragma unroll
          for (int mt = 0; mt < 4; ++mt)
            acc[mt][nt] = MFMA16(A[mt], Bq, acc[mt][nt]);
        }
      }
      const float qb0 = q_bias[h * 32 + c16];
      const float qb1 = q_bias[h * 32 + 16 + c16];
#pragma unroll
      for (int mt = 0; mt < 4; ++mt) {
#pragma unroll
        for (int j = 0; j < 4; ++j) {
          const int row = mt * 16 + g * 4 + j;  // C layout: row=(lane>>4)*4+reg
          float q0 = acc[mt][0][j] + qb0;
          float q1 = acc[mt][1][j] + qb1;
          float ss = q0 * q0 + q1 * q1;
          ss += __shfl_xor(ss, 1); ss += __shfl_xor(ss, 2);
          ss += __shfl_xor(ss, 4); ss += __shfl_xor(ss, 8);
          const float rn = scale_h * rsqrtf(ss);
          q_s[qsw(row, c16)] = f2bf(q0 * rn);
          q_s[qsw(row, 16 + c16)] = f2bf(q1 * rn);
        }
      }
    }

    // ---- Pass K: K[64,32] = x @ Wk_h (128 MFMA), normalize, -> k_s
    {
      const unsigned short* wk = wqkv_t + (size_t)(512 + h * 32) * 512;
      f32x4 acc[4][2];
#pragma unroll
      for (int mt = 0; mt < 4; ++mt)
#pragma unroll
        for (int nt = 0; nt < 2; ++nt) acc[mt][nt] = zacc;
#pragma unroll
      for (int ks = 0; ks < 16; ++ks) {
        const int k0 = ks * 32 + g * 8;
        bf16x8 A[4];
#pragma unroll
        for (int mt = 0; mt < 4; ++mt)
          A[mt] = *(const bf16x8*)&x_s[xsw(mt * 16 + c16, k0)];
#pragma unroll
        for (int nt = 0; nt < 2; ++nt) {
          const bf16x8 Bk = *(const bf16x8*)&wk[(nt * 16 + c16) * 512 + k0];
#pragma unroll
          for (int mt = 0; mt < 4; ++mt)
            acc[mt][nt] = MFMA16(A[mt], Bk, acc[mt][nt]);
        }
      }
#pragma unroll
      for (int mt = 0; mt < 4; ++mt) {
#pragma unroll
        for (int j = 0; j < 4; ++j) {
          const int row = mt * 16 + g * 4 + j;
          const float k0v = acc[mt][0][j];
          const float k1v = acc[mt][1][j];
          float sk = k0v * k0v + k1v * k1v;
          sk += __shfl_xor(sk, 1); sk += __shfl_xor(sk, 2);
          sk += __shfl_xor(sk, 4); sk += __shfl_xor(sk, 8);
          const float rk = rsqrtf(sk);
          k_s[qsw(row, c16)] = f2bf(k0v * rk);
          k_s[qsw(row, 16 + c16)] = f2bf(k1v * rk);
        }
      }
    }

    // ---- Pass V: V[64,32] = x @ Wv_h (128 MFMA), stored transposed [d][token]
    {
      const unsigned short* wv = wqkv_t + (size_t)(1024 + h * 32) * 512;
      f32x4 acc[4][2];
#pragma unroll
      for (int mt = 0; mt < 4; ++mt)
#pragma unroll
        for (int nt = 0; nt < 2; ++nt) acc[mt][nt] = zacc;
#pragma unroll
      for (int ks = 0; ks < 16; ++ks) {
        const int k0 = ks * 32 + g * 8;
        bf16x8 A[4];
#pragma unroll
        for (int mt = 0; mt < 4; ++mt)
          A[mt] = *(const bf16x8*)&x_s[xsw(mt * 16 + c16, k0)];
#pragma unroll
        for (int nt = 0; nt < 2; ++nt) {
          const bf16x8 Bv = *(const bf16x8*)&wv[(nt * 16 + c16) * 512 + k0];
#pragma unroll
          for (int mt = 0; mt < 4; ++mt)
            acc[mt][nt] = MFMA16(A[mt], Bv, acc[mt][nt]);
        }
      }
      const float vb0 = v_bias[h * 32 + c16];
      const float vb1 = v_bias[h * 32 + 16 + c16];
#pragma unroll
      for (int mt = 0; mt < 4; ++mt) {
#pragma unroll
        for (int j = 0; j < 4; ++j) {
          const int row = mt * 16 + g * 4 + j;
          v_slot[psw(c16, row)] = f2bf(acc[mt][0][j] + vb0);
          v_slot[psw(16 + c16, row)] = f2bf(acc[mt][1][j] + vb1);
        }
      }
    }

    // ---- Stage B: S = Qn @ Kn^T, per row-tile (mt) to cap register
    //      pressure at ~70 (R6 held all 16 S f32x4 + frags + 32 scalar
    //      bias/mask loads -> spills). A4/Bk4 prefetched BEFORE any P
    //      write: P overlays q_s|k_s.
    {
      const float* bt = bias_tab + (size_t)h * 4096;
      bf16x8 A4[4], Bk4[4];
#pragma unroll
      for (int mt = 0; mt < 4; ++mt)
        A4[mt] = *(const bf16x8*)&q_s[qsw(mt * 16 + c16, g * 8)];
#pragma unroll
      for (int nt = 0; nt < 4; ++nt)
        Bk4[nt] = *(const bf16x8*)&k_s[qsw(nt * 16 + c16, g * 8)];
#pragma unroll
      for (int mt = 0; mt < 4; ++mt) {
        f32x4 S[4];
#pragma unroll
        for (int nt = 0; nt < 4; ++nt)
          S[nt] = MFMA16(A4[mt], Bk4[nt], zacc);
#pragma unroll
        for (int j = 0; j < 4; ++j) {
          const int r = mt * 16 + g * 4 + j;
#pragma unroll
          for (int nt = 0; nt < 4; ++nt) {
            const int c = nt * 16 + c16;
            S[nt][j] += bt[r * 64 + c] + mk[r * 64 + c];
          }
        }
#pragma unroll
        for (int j = 0; j < 4; ++j) {
          float m0 = fmaxf(fmaxf(S[0][j], S[1][j]), fmaxf(S[2][j], S[3][j]));
          m0 = fmaxf(m0, __shfl_xor(m0, 1));
          m0 = fmaxf(m0, __shfl_xor(m0, 2));
          m0 = fmaxf(m0, __shfl_xor(m0, 4));
          m0 = fmaxf(m0, __shfl_xor(m0, 8));
          float sum = 0.f;
#pragma unroll
          for (int nt = 0; nt < 4; ++nt) {
            const float p = __expf(S[nt][j] - m0);
            S[nt][j] = p;
            sum += p;
          }
          sum += __shfl_xor(sum, 1); sum += __shfl_xor(sum, 2);
          sum += __shfl_xor(sum, 4); sum += __shfl_xor(sum, 8);
          const float inv = 1.f / sum;
          const int r = mt * 16 + g * 4 + j;
#pragma unroll
          for (int nt = 0; nt < 4; ++nt)
            p_s[psw(r, nt * 16 + c16)] = f2bf(S[nt][j] * inv);
        }
      }
    }

    // ---- Stage C: O = P @ V (16 MFMA), O -> v_slot (V^T dead after reads)
    f32x4 O[4][2];
#pragma unroll
    for (int mt = 0; mt < 4; ++mt)
#pragma unroll
      for (int nt = 0; nt < 2; ++nt) O[mt][nt] = zacc;
#pragma unroll
    for (int ks = 0; ks < 2; ++ks) {
      bf16x8 A[4], B2[2];
#pragma unroll
      for (int mt = 0; mt < 4; ++mt)
        A[mt] = *(const bf16x8*)&p_s[psw(mt * 16 + c16, ks * 32 + g * 8)];
#pragma unroll
      for (int nt = 0; nt < 2; ++nt)
        B2[nt] = *(const bf16x8*)&v_slot[psw(nt * 16 + c16, ks * 32 + g * 8)];
#pragma unroll
      for (int mt = 0; mt < 4; ++mt)
#pragma unroll
        for (int nt = 0; nt < 2; ++nt)
          O[mt][nt] = MFMA16(A[mt], B2[nt], O[mt][nt]);
    }
#pragma unroll
    for (int mt = 0; mt < 4; ++mt)
#pragma unroll
      for (int j = 0; j < 4; ++j) {
        const int row = mt * 16 + g * 4 + j;
        v_slot[qsw(row, c16)] = f2bf(O[mt][0][j]);
        v_slot[qsw(row, 16 + c16)] = f2bf(O[mt][1][j]);
      }

    // ---- O store: wave-private LDS -> global, 8 B per lane per iter
#pragma unroll
    for (int i = 0; i < 8; ++i) {
      const int chunk = i * 64 + lane;
      const int r = chunk >> 3;
      const int c4 = (chunk & 7) << 2;
      const ushort4 v = *(const ushort4*)&v_slot[qsw(r, c4)];
      *(ushort4*)&ow[r * 512 + h * 32 + c4] = v;
    }
  }
}

// ---------------------------------------------------------------- proj_gemm
// Per window: stage O16 [64][512] -> LDS (xsw), then out = O @ proj_t + b,
// overwriting the window region with f32. 4 waves, each does two 64-col strips.
__global__ __launch_bounds__(256, 2) void proj_gemm(
    const unsigned short* __restrict__ proj_t,
    const float* __restrict__ proj_b,
    float* __restrict__ out) {
  __shared__ __align__(16) unsigned short o_s[64 * 512];  // 64 KB

  const int tid = threadIdx.x;
  const int wid = tid >> 6;
  const int lane = tid & 63;
  const int c16 = lane & 15;
  const int g = lane >> 4;
  const int b = blockIdx.x;

  const unsigned short* ow = (const unsigned short*)out + (size_t)b * 65536;
  float* og = out + (size_t)b * 32768;

  // stage O16 -> LDS swizzled: 4096 chunks of 8 ushorts (full 64x512 tile)
#pragma unroll
  for (int i = 0; i < 16; ++i) {
    const int ch = i * 256 + tid;          // 8-ushort chunk id, 4096 total
    const int r = ch >> 6;                 // 64 chunks of 8 per row
    const int k = (ch & 63) << 3;
    const ushort4 lo = *(const ushort4*)&ow[ch * 8];
    const ushort4 hi = *(const ushort4*)&ow[ch * 8 + 4];
    *(ushort4*)&o_s[xsw(r, k)] = lo;
    *(ushort4*)&o_s[xsw(r, k) + 4] = hi;
  }
  __syncthreads();

  const f32x4 zacc = {0.f, 0.f, 0.f, 0.f};
#pragma unroll
  for (int half = 0; half < 2; ++half) {
    const int c0 = half * 256 + wid * 64;
    f32x4 outacc[4][4];
#pragma unroll
    for (int mt = 0; mt < 4; ++mt)
#pragma unroll
      for (int nt = 0; nt < 4; ++nt) outacc[mt][nt] = zacc;
#pragma unroll
    for (int ks = 0; ks < 16; ++ks) {
      const int k0 = ks * 32 + g * 8;
      bf16x8 A[4];
#pragma unroll
      for (int mt = 0; mt < 4; ++mt)
        A[mt] = *(const bf16x8*)&o_s[xsw(mt * 16 + c16, k0)];
#pragma unroll
      for (int nt = 0; nt < 4; ++nt) {
        const bf16x8 Bf = *(const bf16x8*)&proj_t[(size_t)(c0 + nt * 16 + c16) * 512 + k0];
#pragma unroll
        for (int mt = 0; mt < 4; ++mt)
          outacc[mt][nt] = MFMA16(A[mt], Bf, outacc[mt][nt]);
      }
    }
    // f32 writes clobber O16 bytes, but all O reads come from LDS -> safe.
#pragma unroll
    for (int nt = 0; nt < 4; ++nt) {
      const int c = c0 + nt * 16 + c16;
      const float pb = proj_b[c];
#pragma unroll
      for (int mt = 0; mt < 4; ++mt) {
#pragma unroll
        for (int j = 0; j < 4; ++j) {
          const int r = mt * 16 + g * 4 + j;
          og[r * 512 + c] = outacc[mt][nt][j] + pb;
        }
      }
    }
  }
}

// ---------------------------------------------------------------- launch
extern "C" void kernel_launch(void* const* d_in, const int* in_sizes, int n_in,
                              void* d_out, int out_size, void* d_ws, size_t ws_size,
                              hipStream_t stream) {
  const float* x = (const float*)d_in[0];
  const float* mask = (const float*)d_in[1];
  const float* rel_table = (const float*)d_in[2];
  const float* w_qkv = (const float*)d_in[3];
  const float* q_bias = (const float*)d_in[4];
  const float* v_bias = (const float*)d_in[5];
  const float* logit_scale = (const float*)d_in[6];
  const float* cpb_w1 = (const float*)d_in[7];
  const float* cpb_b1 = (const float*)d_in[8];
  const float* cpb_w2 = (const float*)d_in[9];
  const float* proj_w = (const float*)d_in[10];
  const float* proj_b = (const float*)d_in[11];

  char* ws = (char*)d_ws;
  float* bias_tab = (float*)(ws);
  unsigned short* wqkv_t = (unsigned short*)(ws + 262144);
  unsigned short* proj_t = (unsigned short*)(ws + 262144 + 1572864);
  float* tab225 = (float*)(ws + 262144 + 1572864 + 524288);

  unsigned short* outu = (unsigned short*)d_out;

  prep1<<<2273, 256, 0, stream>>>(rel_table, w_qkv, proj_w, cpb_w1, cpb_b1, cpb_w2,
                                  wqkv_t, proj_t, tab225);
  prep2<<<16, 256, 0, stream>>>(tab225, bias_tab);
  win_attn<<<2048, 512, 0, stream>>>(x, mask, q_bias, v_bias, logit_scale,
                                     wqkv_t, bias_tab, outu);
  proj_gemm<<<2048, 256, 0, stream>>>(proj_t, proj_b, (float*)d_out);
}